// Round 13
// baseline (1806.496 us; speedup 1.0000x reference)
//
#include <hip/hip_runtime.h>
#include <hip/hip_fp16.h>
#include <cmath>

typedef _Float16 h2 __attribute__((ext_vector_type(2)));
typedef _Float16 f16x8 __attribute__((ext_vector_type(8)));
typedef float f32x4 __attribute__((ext_vector_type(4)));

#define MFMA16 __builtin_amdgcn_mfma_f32_16x16x32_f16

#if defined(__has_builtin)
#if __has_builtin(__builtin_amdgcn_fdot2)
#define HAS_FDOT2 1
#endif
#endif

__device__ __forceinline__ float fdot2f(h2 a, h2 b, float c) {
#ifdef HAS_FDOT2
    return __builtin_amdgcn_fdot2(a, b, c, false);
#else
    c = fmaf((float)a[0], (float)b[0], c);
    return fmaf((float)a[1], (float)b[1], c);
#endif
}

__device__ __forceinline__ float sigm(float x) { return 1.0f / (1.0f + expf(-x)); }
__device__ __forceinline__ unsigned short f16b(float x) {
    _Float16 h = (_Float16)x; return __builtin_bit_cast(unsigned short, h);
}

// ---- weight conversion: fp32 -> k-pair-packed f16 -------------------------------
__global__ __launch_bounds__(256) void convert_weights(
    const float* __restrict__ gate_k, const float* __restrict__ cand_k,
    float* __restrict__ gkh, float* __restrict__ ckh)
{
    int i = blockIdx.x * 256 + threadIdx.x;
    if (i < 8 * 256 * 512) {
        int col = i & 511, kp = (i >> 9) & 255, e2 = i >> 17;
        const float* src = gate_k + ((size_t)e2 * 512 + 2 * kp) * 512 + col;
        h2 v; v[0] = (_Float16)src[0]; v[1] = (_Float16)src[512];
        gkh[i] = __builtin_bit_cast(float, v);
    }
    if (i < 8 * 256 * 256) {
        int col = i & 255, kp = (i >> 8) & 255, e2 = i >> 16;
        const float* src = cand_k + ((size_t)e2 * 512 + 2 * kp) * 256 + col;
        h2 v; v[0] = (_Float16)src[0]; v[1] = (_Float16)src[256];
        ckh[i] = __builtin_bit_cast(float, v);
    }
}

// ---- Wprod pack into per-lane MFMA B-fragment layout ----------------------------
__global__ __launch_bounds__(256) void conv_wprod(const float* __restrict__ w1,
                                                  f16x8* __restrict__ wB)
{
    int i = blockIdx.x * 256 + threadIdx.x;   // [kt 32][nt 64][l 64]
    int l = i & 63, nt = (i >> 6) & 63, kt = i >> 12;
    int k0 = kt*32 + ((l >> 4) << 3);
    int n  = (nt << 4) + (l & 15);
    const float* src = w1 + (size_t)(2049 + k0) * 1024 + n;
    f16x8 v;
    #pragma unroll
    for (int j = 0; j < 8; ++j) v[j] = (_Float16)src[(size_t)j * 1024];
    wB[i] = v;
}

// ---- precompute layer-1 x contributions: XG = X@gkx, XC = X@ckx (MFMA) ----------
// m = b*64 + t (per encoder); A[m][k] = emb[tok(e,b,t)][k], k<256 (x = FIRST 256 rows)
__global__ __launch_bounds__(512) void precompute_x(
    const int* __restrict__ iq, const int* __restrict__ ir,
    const int* __restrict__ ql, const int* __restrict__ rl,
    const float* __restrict__ emb,
    const float* __restrict__ gate_k, const float* __restrict__ cand_k,
    _Float16* __restrict__ xg, _Float16* __restrict__ xc)
{
    int mtile = blockIdx.x;       // 0..63 (128 m-rows each)
    int nt    = blockIdx.y;       // 0..5: 0-3 gate cols, 4-5 cand cols
    int enc   = blockIdx.z;       // 0..3
    int tid = threadIdx.x, w = tid >> 6, l = tid & 63;
    const int* toks = (enc < 2) ? iq : ir;
    const int* lens = (enc < 2) ? ql : rl;
    const bool bw = (enc & 1);
    const bool isg = (nt < 4);
    int n0 = isg ? nt * 128 : (nt - 4) * 128;
    int nstride = isg ? 512 : 256;
    const float* W = isg ? (gate_k + (size_t)(enc * 2) * 512 * 512)
                         : (cand_k + (size_t)(enc * 2) * 512 * 256);
    _Float16* dst = isg ? (xg + (size_t)enc * 8192 * 512)
                        : (xc + (size_t)enc * 8192 * 256);

    __shared__ int tok_l[128];
    __shared__ __align__(16) unsigned short As[4096];   // [128 rows][32 k], kg ^ (row&3)

    if (tid < 128) {
        int b = mtile * 2 + (tid >> 6), t = tid & 63;
        int len = lens[b];
        int tt = bw ? ((t < len) ? (len - 1 - t) : t) : t;
        tok_l[tid] = toks[b * 64 + tt];
    }
    __syncthreads();

    int srow = tid & 127, skg = tid >> 7;   // A-staging mapping

    f32x4 acc[8];
    #pragma unroll
    for (int m = 0; m < 8; ++m) acc[m] = (f32x4){0.f, 0.f, 0.f, 0.f};

    for (int kt = 0; kt < 8; ++kt) {
        const float* es = emb + (size_t)tok_l[srow] * 256 + kt * 32 + skg * 8;
        float4 e0 = *(const float4*)es;
        float4 e1 = *(const float4*)(es + 4);
        f16x8 av;
        av[0]=(_Float16)e0.x; av[1]=(_Float16)e0.y; av[2]=(_Float16)e0.z; av[3]=(_Float16)e0.w;
        av[4]=(_Float16)e1.x; av[5]=(_Float16)e1.y; av[6]=(_Float16)e1.z; av[7]=(_Float16)e1.w;
        __syncthreads();
        ((f16x8*)As)[srow * 4 + (skg ^ (srow & 3))] = av;
        __syncthreads();

        const float* wp = W + (size_t)(kt * 32 + (l >> 4) * 8) * nstride + n0 + w * 16 + (l & 15);
        f16x8 bf;
        #pragma unroll
        for (int j = 0; j < 8; ++j) bf[j] = (_Float16)wp[(size_t)j * nstride];
        #pragma unroll
        for (int mt = 0; mt < 8; ++mt) {
            f16x8 af = ((const f16x8*)As)[(mt * 16 + (l & 15)) * 4 + ((l >> 4) ^ (l & 3))];
            acc[mt] = MFMA16(af, bf, acc[mt], 0, 0, 0);
        }
    }

    int ncol = n0 + w * 16 + (l & 15);
    #pragma unroll
    for (int mt = 0; mt < 8; ++mt) {
        #pragma unroll
        for (int j = 0; j < 4; ++j) {
            int m = mtile * 128 + mt * 16 + (l >> 4) * 4 + j;
            dst[(size_t)m * nstride + ncol] = (_Float16)acc[mt][j];
        }
    }
}

// ---- GRU hot loops (f16 dot2) ----------------------------------------------------
// in0f layout: f16 element (k, row) at  (k>>1)*8 + row*2 + (k&1)
__device__ __forceinline__ void gate_partial_h(
    const _Float16* in0f, float* pbuf, const float* __restrict__ gk, int tid)
{
    int cg = tid & 127, q = tid >> 7;
    int c0 = cg * 4;
    const float* gp = gk + (size_t)(q * 32) * 512 + c0;
    const _Float16* xp = in0f + q * 32 * 8;
    float4 A0 = {0.f,0.f,0.f,0.f}, A1 = {0.f,0.f,0.f,0.f};
    float4 A2 = {0.f,0.f,0.f,0.f}, A3 = {0.f,0.f,0.f,0.f};
    #pragma unroll 8
    for (int i = 0; i < 32; ++i) {
        float4 wf = *(const float4*)(gp + (size_t)i * 512);
        float4 xf = *(const float4*)(xp + i * 8);
        h2 w0 = __builtin_bit_cast(h2, wf.x), w1 = __builtin_bit_cast(h2, wf.y);
        h2 w2 = __builtin_bit_cast(h2, wf.z), w3 = __builtin_bit_cast(h2, wf.w);
        h2 x0 = __builtin_bit_cast(h2, xf.x), x1 = __builtin_bit_cast(h2, xf.y);
        h2 x2 = __builtin_bit_cast(h2, xf.z), x3 = __builtin_bit_cast(h2, xf.w);
        A0.x = fdot2f(x0, w0, A0.x); A0.y = fdot2f(x0, w1, A0.y);
        A0.z = fdot2f(x0, w2, A0.z); A0.w = fdot2f(x0, w3, A0.w);
        A1.x = fdot2f(x1, w0, A1.x); A1.y = fdot2f(x1, w1, A1.y);
        A1.z = fdot2f(x1, w2, A1.z); A1.w = fdot2f(x1, w3, A1.w);
        A2.x = fdot2f(x2, w0, A2.x); A2.y = fdot2f(x2, w1, A2.y);
        A2.z = fdot2f(x2, w2, A2.z); A2.w = fdot2f(x2, w3, A2.w);
        A3.x = fdot2f(x3, w0, A3.x); A3.y = fdot2f(x3, w1, A3.y);
        A3.z = fdot2f(x3, w2, A3.z); A3.w = fdot2f(x3, w3, A3.w);
    }
    *(float4*)&pbuf[(q * 4 + 0) * 512 + c0] = A0;
    *(float4*)&pbuf[(q * 4 + 1) * 512 + c0] = A1;
    *(float4*)&pbuf[(q * 4 + 2) * 512 + c0] = A2;
    *(float4*)&pbuf[(q * 4 + 3) * 512 + c0] = A3;
}

// half-K variant: dots over the h-half only (kp 128..255)
__device__ __forceinline__ void gate_partial_h_half(
    const _Float16* in0f, float* pbuf, const float* __restrict__ gk, int tid)
{
    int cg = tid & 127, q = tid >> 7;    // q 0..7, 16 kp each
    int c0 = cg * 4;
    const float* gp = gk + (size_t)(128 + q * 16) * 512 + c0;
    const _Float16* xp = in0f + (128 + q * 16) * 8;
    float4 A0 = {0.f,0.f,0.f,0.f}, A1 = {0.f,0.f,0.f,0.f};
    float4 A2 = {0.f,0.f,0.f,0.f}, A3 = {0.f,0.f,0.f,0.f};
    #pragma unroll
    for (int i = 0; i < 16; ++i) {
        float4 wf = *(const float4*)(gp + (size_t)i * 512);
        float4 xf = *(const float4*)(xp + i * 8);
        h2 w0 = __builtin_bit_cast(h2, wf.x), w1 = __builtin_bit_cast(h2, wf.y);
        h2 w2 = __builtin_bit_cast(h2, wf.z), w3 = __builtin_bit_cast(h2, wf.w);
        h2 x0 = __builtin_bit_cast(h2, xf.x), x1 = __builtin_bit_cast(h2, xf.y);
        h2 x2 = __builtin_bit_cast(h2, xf.z), x3 = __builtin_bit_cast(h2, xf.w);
        A0.x = fdot2f(x0, w0, A0.x); A0.y = fdot2f(x0, w1, A0.y);
        A0.z = fdot2f(x0, w2, A0.z); A0.w = fdot2f(x0, w3, A0.w);
        A1.x = fdot2f(x1, w0, A1.x); A1.y = fdot2f(x1, w1, A1.y);
        A1.z = fdot2f(x1, w2, A1.z); A1.w = fdot2f(x1, w3, A1.w);
        A2.x = fdot2f(x2, w0, A2.x); A2.y = fdot2f(x2, w1, A2.y);
        A2.z = fdot2f(x2, w2, A2.z); A2.w = fdot2f(x2, w3, A2.w);
        A3.x = fdot2f(x3, w0, A3.x); A3.y = fdot2f(x3, w1, A3.y);
        A3.z = fdot2f(x3, w2, A3.z); A3.w = fdot2f(x3, w3, A3.w);
    }
    *(float4*)&pbuf[(q * 4 + 0) * 512 + c0] = A0;
    *(float4*)&pbuf[(q * 4 + 1) * 512 + c0] = A1;
    *(float4*)&pbuf[(q * 4 + 2) * 512 + c0] = A2;
    *(float4*)&pbuf[(q * 4 + 3) * 512 + c0] = A3;
}

__device__ __forceinline__ void cand_partial_h(
    const _Float16* in0f, float* pbuf, const float* __restrict__ ck, int tid)
{
    int cg = tid & 63, q = tid >> 6;
    int c0 = cg * 4;
    const float* cp = ck + (size_t)(q * 16) * 256 + c0;
    const _Float16* xp = in0f + q * 16 * 8;
    float4 A0 = {0.f,0.f,0.f,0.f}, A1 = {0.f,0.f,0.f,0.f};
    float4 A2 = {0.f,0.f,0.f,0.f}, A3 = {0.f,0.f,0.f,0.f};
    #pragma unroll 8
    for (int i = 0; i < 16; ++i) {
        float4 wf = *(const float4*)(cp + (size_t)i * 256);
        float4 xf = *(const float4*)(xp + i * 8);
        h2 w0 = __builtin_bit_cast(h2, wf.x), w1 = __builtin_bit_cast(h2, wf.y);
        h2 w2 = __builtin_bit_cast(h2, wf.z), w3 = __builtin_bit_cast(h2, wf.w);
        h2 x0 = __builtin_bit_cast(h2, xf.x), x1 = __builtin_bit_cast(h2, xf.y);
        h2 x2 = __builtin_bit_cast(h2, xf.z), x3 = __builtin_bit_cast(h2, xf.w);
        A0.x = fdot2f(x0, w0, A0.x); A0.y = fdot2f(x0, w1, A0.y);
        A0.z = fdot2f(x0, w2, A0.z); A0.w = fdot2f(x0, w3, A0.w);
        A1.x = fdot2f(x1, w0, A1.x); A1.y = fdot2f(x1, w1, A1.y);
        A1.z = fdot2f(x1, w2, A1.z); A1.w = fdot2f(x1, w3, A1.w);
        A2.x = fdot2f(x2, w0, A2.x); A2.y = fdot2f(x2, w1, A2.y);
        A2.z = fdot2f(x2, w2, A2.z); A2.w = fdot2f(x2, w3, A2.w);
        A3.x = fdot2f(x3, w0, A3.x); A3.y = fdot2f(x3, w1, A3.y);
        A3.z = fdot2f(x3, w2, A3.z); A3.w = fdot2f(x3, w3, A3.w);
    }
    *(float4*)&pbuf[(q * 4 + 0) * 256 + c0] = A0;
    *(float4*)&pbuf[(q * 4 + 1) * 256 + c0] = A1;
    *(float4*)&pbuf[(q * 4 + 2) * 256 + c0] = A2;
    *(float4*)&pbuf[(q * 4 + 3) * 256 + c0] = A3;
}

// half-K variant (kp 128..255 = r*h half)
__device__ __forceinline__ void cand_partial_h_half(
    const _Float16* in0f, float* pbuf, const float* __restrict__ ck, int tid)
{
    int cg = tid & 63, q = tid >> 6;     // q 0..15, 8 kp each
    int c0 = cg * 4;
    const float* cp = ck + (size_t)(128 + q * 8) * 256 + c0;
    const _Float16* xp = in0f + (128 + q * 8) * 8;
    float4 A0 = {0.f,0.f,0.f,0.f}, A1 = {0.f,0.f,0.f,0.f};
    float4 A2 = {0.f,0.f,0.f,0.f}, A3 = {0.f,0.f,0.f,0.f};
    #pragma unroll
    for (int i = 0; i < 8; ++i) {
        float4 wf = *(const float4*)(cp + (size_t)i * 256);
        float4 xf = *(const float4*)(xp + i * 8);
        h2 w0 = __builtin_bit_cast(h2, wf.x), w1 = __builtin_bit_cast(h2, wf.y);
        h2 w2 = __builtin_bit_cast(h2, wf.z), w3 = __builtin_bit_cast(h2, wf.w);
        h2 x0 = __builtin_bit_cast(h2, xf.x), x1 = __builtin_bit_cast(h2, xf.y);
        h2 x2 = __builtin_bit_cast(h2, xf.z), x3 = __builtin_bit_cast(h2, xf.w);
        A0.x = fdot2f(x0, w0, A0.x); A0.y = fdot2f(x0, w1, A0.y);
        A0.z = fdot2f(x0, w2, A0.z); A0.w = fdot2f(x0, w3, A0.w);
        A1.x = fdot2f(x1, w0, A1.x); A1.y = fdot2f(x1, w1, A1.y);
        A1.z = fdot2f(x1, w2, A1.z); A1.w = fdot2f(x1, w3, A1.w);
        A2.x = fdot2f(x2, w0, A2.x); A2.y = fdot2f(x2, w1, A2.y);
        A2.z = fdot2f(x2, w2, A2.z); A2.w = fdot2f(x2, w3, A2.w);
        A3.x = fdot2f(x3, w0, A3.x); A3.y = fdot2f(x3, w1, A3.y);
        A3.z = fdot2f(x3, w2, A3.z); A3.w = fdot2f(x3, w3, A3.w);
    }
    *(float4*)&pbuf[(q * 4 + 0) * 256 + c0] = A0;
    *(float4*)&pbuf[(q * 4 + 1) * 256 + c0] = A1;
    *(float4*)&pbuf[(q * 4 + 2) * 256 + c0] = A2;
    *(float4*)&pbuf[(q * 4 + 3) * 256 + c0] = A3;
}

// ---- gru_encode with precomputed x-contributions (layer 1 dots h-half only) -----
__global__ __launch_bounds__(1024, 4) void gru_encode_px(
    const int* __restrict__ ql, const int* __restrict__ rl,
    const float* __restrict__ gkh, const float* __restrict__ gate_b,
    const float* __restrict__ ckh, const float* __restrict__ cand_b,
    const _Float16* __restrict__ xg, const _Float16* __restrict__ xc,
    float* __restrict__ Qo, float* __restrict__ Ro)
{
    int bid = blockIdx.x;
    int xcd = bid & 7;
    int enc = xcd >> 1;
    int chunk = (xcd & 1) * 16 + (bid >> 3);
    int b0 = chunk * 4;
    int tid = threadIdx.x;
    int c = tid & 255, r = tid >> 8;

    const int* lens = (enc < 2) ? ql : rl;

    const float* gk1 = gkh + (size_t)(enc * 2 + 0) * 131072;
    const float* gk2 = gkh + (size_t)(enc * 2 + 1) * 131072;
    const float* gb1 = gate_b + (enc * 2 + 0) * 512;
    const float* gb2 = gate_b + (enc * 2 + 1) * 512;
    const float* ck1 = ckh + (size_t)(enc * 2 + 0) * 65536;
    const float* ck2 = ckh + (size_t)(enc * 2 + 1) * 65536;
    const float* cb1 = cand_b + (enc * 2 + 0) * 256;
    const float* cb2 = cand_b + (enc * 2 + 1) * 256;
    const _Float16* xgE = xg + (size_t)enc * 8192 * 512;
    const _Float16* xcE = xc + (size_t)enc * 8192 * 256;

    __shared__ __align__(16) _Float16 in0f[256 * 8];
    __shared__ float pbuf[16384];
    __shared__ float h1rt[4][256];
    __shared__ float h2rt[4][256];
    __shared__ float gzt[4][256];
    __shared__ int len_s[4];

    h1rt[r][c] = 0.f;
    h2rt[r][c] = 0.f;
    if (tid < 4) len_s[tid] = lens[b0 + tid];
    __syncthreads();
    int maxlen = max(max(len_s[0], len_s[1]), max(len_s[2], len_s[3]));

    for (int t = 0; t < maxlen; ++t) {
        // FILL: stage h1 into the h-half of in0f (x never staged — precomputed)
        if (tid < 512) {
            int m = tid >> 2, rr = tid & 3;
            h2 v; v[0] = (_Float16)h1rt[rr][2 * m]; v[1] = (_Float16)h1rt[rr][2 * m + 1];
            *(float*)(in0f + (128 + m) * 8 + rr * 2) = __builtin_bit_cast(float, v);
        }
        __syncthreads();

        // ---- layer 1 (h-half dots + precomputed x) ----
        gate_partial_h_half(in0f, pbuf, gk1, tid);
        __syncthreads();
        {
            const _Float16* xgp = xgE + ((size_t)(b0 + r) * 64 + t) * 512;
            float s0 = gb1[c] + (float)xgp[c];
            float s1 = gb1[256 + c] + (float)xgp[256 + c];
            #pragma unroll
            for (int q = 0; q < 8; ++q) {
                s0 += pbuf[(q * 4 + r) * 512 + c];
                s1 += pbuf[(q * 4 + r) * 512 + c + 256];
            }
            float rh = sigm(s0) * h1rt[r][c];
            gzt[r][c] = sigm(s1);
            in0f[((256 + c) >> 1) * 8 + r * 2 + (c & 1)] = (_Float16)rh;
        }
        __syncthreads();
        cand_partial_h_half(in0f, pbuf, ck1, tid);
        __syncthreads();
        {
            const _Float16* xcp = xcE + ((size_t)(b0 + r) * 64 + t) * 256;
            float s = cb1[c] + (float)xcp[c];
            #pragma unroll
            for (int q = 0; q < 16; ++q) s += pbuf[(q * 4 + r) * 256 + c];
            float cv = tanhf(s);
            float z = gzt[r][c];
            float hn = fmaf(z, h1rt[r][c] - cv, cv);
            if (t < len_s[r]) h1rt[r][c] = hn;
            in0f[(c >> 1) * 8 + r * 2 + (c & 1)]         = (_Float16)hn;       // layer-2 x
            in0f[((256 + c) >> 1) * 8 + r * 2 + (c & 1)] = (_Float16)h2rt[r][c]; // layer-2 h
        }
        __syncthreads();

        // ---- layer 2 (full K) ----
        gate_partial_h(in0f, pbuf, gk2, tid);
        __syncthreads();
        {
            float s0 = gb2[c], s1 = gb2[256 + c];
            #pragma unroll
            for (int q = 0; q < 8; ++q) {
                s0 += pbuf[(q * 4 + r) * 512 + c];
                s1 += pbuf[(q * 4 + r) * 512 + c + 256];
            }
            float rh = sigm(s0) * h2rt[r][c];
            gzt[r][c] = sigm(s1);
            in0f[((256 + c) >> 1) * 8 + r * 2 + (c & 1)] = (_Float16)rh;
        }
        __syncthreads();
        cand_partial_h(in0f, pbuf, ck2, tid);
        __syncthreads();
        {
            float s = cb2[c];
            #pragma unroll
            for (int q = 0; q < 16; ++q) s += pbuf[(q * 4 + r) * 256 + c];
            float cv = tanhf(s);
            float z = gzt[r][c];
            float hn = fmaf(z, h2rt[r][c] - cv, cv);
            if (t < len_s[r]) h2rt[r][c] = hn;
        }
        __syncthreads();
    }

    float* outp = (enc < 2) ? Qo : Ro;
    int off = (enc & 1) ? 512 : 0;
    outp[(size_t)(b0 + r) * 1024 + off + c]       = h1rt[r][c];
    outp[(size_t)(b0 + r) * 1024 + off + 256 + c] = h2rt[r][c];
}

// ---- round-12 gru_encode (fallback when ws too small for XG/XC) -----------------
__global__ __launch_bounds__(1024, 4) void gru_encode(
    const int* __restrict__ iq, const int* __restrict__ ir,
    const int* __restrict__ ql, const int* __restrict__ rl,
    const float* __restrict__ emb,
    const float* __restrict__ gkh, const float* __restrict__ gate_b,
    const float* __restrict__ ckh, const float* __restrict__ cand_b,
    float* __restrict__ Qo, float* __restrict__ Ro)
{
    int bid = blockIdx.x;
    int xcd = bid & 7;
    int enc = xcd >> 1;
    int chunk = (xcd & 1) * 16 + (bid >> 3);
    int b0 = chunk * 4;
    int tid = threadIdx.x;
    int c = tid & 255, r = tid >> 8;

    const int* toks = (enc < 2) ? iq : ir;
    const int* lens = (enc < 2) ? ql : rl;
    const bool bw = (enc & 1);

    const float* gk1 = gkh + (size_t)(enc * 2 + 0) * 131072;
    const float* gk2 = gkh + (size_t)(enc * 2 + 1) * 131072;
    const float* gb1 = gate_b + (enc * 2 + 0) * 512;
    const float* gb2 = gate_b + (enc * 2 + 1) * 512;
    const float* ck1 = ckh + (size_t)(enc * 2 + 0) * 65536;
    const float* ck2 = ckh + (size_t)(enc * 2 + 1) * 65536;
    const float* cb1 = cand_b + (enc * 2 + 0) * 256;
    const float* cb2 = cand_b + (enc * 2 + 1) * 256;

    __shared__ __align__(16) _Float16 in0f[256 * 8];
    __shared__ float pbuf[16384];
    __shared__ float h1rt[4][256];
    __shared__ float h2rt[4][256];
    __shared__ float gzt[4][256];
    __shared__ int tok_s[4];
    __shared__ int len_s[4];

    h1rt[r][c] = 0.f;
    h2rt[r][c] = 0.f;
    if (tid < 4) len_s[tid] = lens[b0 + tid];
    __syncthreads();
    int maxlen = max(max(len_s[0], len_s[1]), max(len_s[2], len_s[3]));
    if (tid < 4) {
        int len = len_s[tid];
        tok_s[tid] = toks[(b0 + tid) * 64 + (bw ? (len - 1) : 0)];
    }
    __syncthreads();

    for (int t = 0; t < maxlen; ++t) {
        if (tid < 512) {
            int kp = tid >> 2, rr = tid & 3;
            float2 xv = *(const float2*)(emb + (size_t)tok_s[rr] * 256 + 2 * kp);
            h2 v; v[0] = (_Float16)xv.x; v[1] = (_Float16)xv.y;
            *(float*)(in0f + kp * 8 + rr * 2) = __builtin_bit_cast(float, v);
        } else {
            int m = (tid - 512) >> 2, rr = tid & 3;
            h2 v; v[0] = (_Float16)h1rt[rr][2 * m]; v[1] = (_Float16)h1rt[rr][2 * m + 1];
            *(float*)(in0f + (128 + m) * 8 + rr * 2) = __builtin_bit_cast(float, v);
        }
        __syncthreads();

        gate_partial_h(in0f, pbuf, gk1, tid);
        __syncthreads();
        {
            float s0 = gb1[c], s1 = gb1[256 + c];
            #pragma unroll
            for (int q = 0; q < 8; ++q) {
                s0 += pbuf[(q * 4 + r) * 512 + c];
                s1 += pbuf[(q * 4 + r) * 512 + c + 256];
            }
            float rh = sigm(s0) * h1rt[r][c];
            gzt[r][c] = sigm(s1);
            in0f[((256 + c) >> 1) * 8 + r * 2 + (c & 1)] = (_Float16)rh;
        }
        __syncthreads();
        cand_partial_h(in0f, pbuf, ck1, tid);
        __syncthreads();
        {
            float s = cb1[c];
            #pragma unroll
            for (int q = 0; q < 16; ++q) s += pbuf[(q * 4 + r) * 256 + c];
            float cv = tanhf(s);
            float z = gzt[r][c];
            float hn = fmaf(z, h1rt[r][c] - cv, cv);
            if (t < len_s[r]) h1rt[r][c] = hn;
            in0f[(c >> 1) * 8 + r * 2 + (c & 1)]         = (_Float16)hn;
            in0f[((256 + c) >> 1) * 8 + r * 2 + (c & 1)] = (_Float16)h2rt[r][c];
        }
        __syncthreads();

        gate_partial_h(in0f, pbuf, gk2, tid);
        __syncthreads();
        {
            float s0 = gb2[c], s1 = gb2[256 + c];
            #pragma unroll
            for (int q = 0; q < 8; ++q) {
                s0 += pbuf[(q * 4 + r) * 512 + c];
                s1 += pbuf[(q * 4 + r) * 512 + c + 256];
            }
            float rh = sigm(s0) * h2rt[r][c];
            gzt[r][c] = sigm(s1);
            in0f[((256 + c) >> 1) * 8 + r * 2 + (c & 1)] = (_Float16)rh;
        }
        __syncthreads();
        cand_partial_h(in0f, pbuf, ck2, tid);
        __syncthreads();
        {
            float s = cb2[c];
            #pragma unroll
            for (int q = 0; q < 16; ++q) s += pbuf[(q * 4 + r) * 256 + c];
            float cv = tanhf(s);
            float z = gzt[r][c];
            float hn = fmaf(z, h2rt[r][c] - cv, cv);
            if (t < len_s[r]) h2rt[r][c] = hn;
        }
        if (tid < 4) {
            int t2 = t + 1;
            if (t2 < 64) {
                int len = len_s[tid];
                int tt = bw ? ((t2 < len) ? (len - 1 - t2) : t2) : t2;
                tok_s[tid] = toks[(b0 + tid) * 64 + tt];
            }
        }
        __syncthreads();
    }

    float* outp = (enc < 2) ? Qo : Ro;
    int off = (enc & 1) ? 512 : 0;
    outp[(size_t)(b0 + r) * 1024 + off + c]       = h1rt[r][c];
    outp[(size_t)(b0 + r) * 1024 + off + 256 + c] = h2rt[r][c];
}

// ---------------- dist / ab (unchanged fp32) --------------------------------------
__global__ void dist_kernel(const float* __restrict__ Q, const float* __restrict__ R,
                            float* __restrict__ dist)
{
    int gidx = blockIdx.x * 256 + threadIdx.x;
    int i = gidx >> 7, j = gidx & 127;
    const float4* q4 = (const float4*)(Q + (size_t)i * 1024);
    const float4* r4 = (const float4*)(R + (size_t)j * 1024);
    float acc = 0.f;
    for (int k = 0; k < 256; ++k) {
        float4 a = q4[k], b = r4[k];
        acc += a.x * b.x + a.y * b.y + a.z * b.z + a.w * b.w;
    }
    dist[gidx] = acc;
}

__global__ __launch_bounds__(256) void ab_kernel(
    const float* __restrict__ Q, const float* __restrict__ R,
    const float* __restrict__ w1, float* __restrict__ A, float* __restrict__ Bv)
{
    int nb = blockIdx.x, rb = blockIdx.y, mat = blockIdx.z;
    int tid = threadIdx.x;
    int n = nb * 256 + tid;
    int r0 = rb * 16;
    const float* src   = mat ? R : Q;
    const float* wmain = mat ? (w1 + (size_t)3073 * 1024) : w1;
    const float* wdiff = w1 + (size_t)1025 * 1024;
    float sgn = mat ? -1.f : 1.f;

    __shared__ float Qs[16][64];
    float acc[16];
    #pragma unroll
    for (int r = 0; r < 16; ++r) acc[r] = 0.f;

    for (int k0 = 0; k0 < 1024; k0 += 64) {
        __syncthreads();
        #pragma unroll
        for (int s = 0; s < 4; ++s) {
            int e = s * 256 + tid;
            int r = e >> 6, kk = e & 63;
            Qs[r][kk] = src[(size_t)(r0 + r) * 1024 + k0 + kk];
        }
        __syncthreads();
        for (int kk = 0; kk < 64; ++kk) {
            size_t row = (size_t)(k0 + kk) * 1024 + n;
            float w = wmain[row] + sgn * wdiff[row];
            #pragma unroll
            for (int r = 0; r < 16; ++r)
                acc[r] = fmaf(Qs[r][kk], w, acc[r]);
        }
    }
    float* dst = mat ? Bv : A;
    #pragma unroll
    for (int r = 0; r < 16; ++r)
        dst[(size_t)(r0 + r) * 1024 + n] = acc[r];
}

// ---------------- pair GEMM: 128x128 tile MFMA, fused epilogue --------------------
__global__ __launch_bounds__(512, 2) void pair_gemm(
    const float* __restrict__ Q, const float* __restrict__ R,
    const float* __restrict__ Aq, const float* __restrict__ Bv,
    const float* __restrict__ dist,
    const int* __restrict__ nqi, const int* __restrict__ nri,
    const f16x8* __restrict__ wB,
    const float* __restrict__ w1, const float* __restrict__ b1,
    const float* __restrict__ w2, float* __restrict__ partial)
{
    int bm = blockIdx.x, bn = blockIdx.y;
    int tid = threadIdx.x, w = tid >> 6, l = tid & 63;
    __shared__ __align__(16) unsigned short As[4096];
    __shared__ float red[2048];
    __shared__ int qis[128], ris[128];
    __shared__ float dsv[128];
    if (tid < 128) {
        int p = bm*128 + tid;
        int qi = (p < 128) ? p : nqi[p-128];
        int ri = (p < 128) ? p : nri[p-128];
        qis[tid] = qi; ris[tid] = ri; dsv[tid] = dist[qi*128 + ri];
    }
    __syncthreads();

    int srow = tid & 127, skg = tid >> 7;
    const float* qrow = Q + (size_t)qis[srow]*1024 + skg*8;
    const float* rrow = R + (size_t)ris[srow]*1024 + skg*8;

    float4 qa = *(const float4*)(qrow);
    float4 qb = *(const float4*)(qrow + 4);
    float4 ra = *(const float4*)(rrow);
    float4 rb = *(const float4*)(rrow + 4);

    f32x4 acc[8];
    #pragma unroll
    for (int m = 0; m < 8; ++m) acc[m] = (f32x4){0.f,0.f,0.f,0.f};

    for (int kt = 0; kt < 32; ++kt) {
        f16x8 prod;
        prod[0]=(_Float16)(qa.x*ra.x); prod[1]=(_Float16)(qa.y*ra.y);
        prod[2]=(_Float16)(qa.z*ra.z); prod[3]=(_Float16)(qa.w*ra.w);
        prod[4]=(_Float16)(qb.x*rb.x); prod[5]=(_Float16)(qb.y*rb.y);
        prod[6]=(_Float16)(qb.z*rb.z); prod[7]=(_Float16)(qb.w*rb.w);
        __syncthreads();
        ((f16x8*)As)[srow*4 + (skg ^ (srow & 3))] = prod;
        __syncthreads();
        if (kt + 1 < 32) {
            qa = *(const float4*)(qrow + (kt+1)*32);
            qb = *(const float4*)(qrow + (kt+1)*32 + 4);
            ra = *(const float4*)(rrow + (kt+1)*32);
            rb = *(const float4*)(rrow + (kt+1)*32 + 4);
        }
        f16x8 bf = wB[((size_t)kt*64 + bn*8 + w)*64 + l];
        #pragma unroll
        for (int mt = 0; mt < 8; ++mt) {
            f16x8 af = ((const f16x8*)As)[(mt*16 + (l & 15))*4 + ((l >> 4) ^ (l & 3))];
            acc[mt] = MFMA16(af, bf, acc[mt], 0, 0, 0);
        }
    }

    int col = bn*128 + w*16 + (l & 15);
    float wd  = w1[(size_t)1024*1024 + col];
    float b1v = b1[col];
    float w20 = w2[col*2], w21 = w2[col*2 + 1];
    #pragma unroll
    for (int mt = 0; mt < 8; ++mt) {
        float po0[4], po1[4];
        #pragma unroll
        for (int j = 0; j < 4; ++j) {
            int lr = mt*16 + (l >> 4)*4 + j;
            float h = acc[mt][j]
                    + Aq[(size_t)qis[lr]*1024 + col]
                    + Bv[(size_t)ris[lr]*1024 + col]
                    + dsv[lr]*wd + b1v;
            h = fmaxf(h, 0.f);
            po0[j] = h * w20; po1[j] = h * w21;
        }
        #pragma unroll
        for (int s = 1; s < 16; s <<= 1) {
            #pragma unroll
            for (int j = 0; j < 4; ++j) {
                po0[j] += __shfl_xor(po0[j], s, 64);
                po1[j] += __shfl_xor(po1[j], s, 64);
            }
        }
        if ((l & 15) == 0) {
            #pragma unroll
            for (int j = 0; j < 4; ++j) {
                int row = mt*16 + (l >> 4)*4 + j;
                red[(w*128 + row)*2 + 0] = po0[j];
                red[(w*128 + row)*2 + 1] = po1[j];
            }
        }
    }
    __syncthreads();
    if (tid < 256) {
        int row = tid >> 1, cc = tid & 1;
        float s = 0.f;
        #pragma unroll
        for (int ww = 0; ww < 8; ++ww) s += red[(ww*128 + row)*2 + cc];
        partial[((size_t)bn*16384 + bm*128 + row)*2 + cc] = s;
    }
}

__global__ void final_reduce(const float* __restrict__ partial,
                             const float* __restrict__ b2, float* __restrict__ out)
{
    int gidx = blockIdx.x * 256 + threadIdx.x;
    int p = gidx >> 1, c = gidx & 1;
    float s = b2[c];
    #pragma unroll
    for (int nt = 0; nt < 8; ++nt)
        s += partial[((size_t)nt * 16384 + p) * 2 + c];
    out[gidx] = s;
}

extern "C" void kernel_launch(void* const* d_in, const int* in_sizes, int n_in,
                              void* d_out, int out_size, void* d_ws, size_t ws_size,
                              hipStream_t stream) {
    const int*   iq     = (const int*)d_in[0];
    const int*   ir     = (const int*)d_in[1];
    const int*   ql     = (const int*)d_in[2];
    const int*   rl     = (const int*)d_in[3];
    const int*   nqi    = (const int*)d_in[4];
    const int*   nri    = (const int*)d_in[5];
    const float* emb    = (const float*)d_in[6];
    const float* gate_k = (const float*)d_in[7];
    const float* gate_b = (const float*)d_in[8];
    const float* cand_k = (const float*)d_in[9];
    const float* cand_b = (const float*)d_in[10];
    const float* w1     = (const float*)d_in[11];
    const float* b1     = (const float*)d_in[12];
    const float* w2     = (const float*)d_in[13];
    const float* b2     = (const float*)d_in[14];
    float* out = (float*)d_out;
    float* ws  = (float*)d_ws;

    float* Q       = ws;                  // 131072
    float* R       = ws + 131072;         // 131072
    float* A       = ws + 262144;         // 131072
    float* Bv      = ws + 393216;         // 131072
    float* dist    = ws + 524288;         // 16384
    float* partial = ws + 540672;         // 262144
    float* gkh     = ws + 1064960;        // 8*256*512
    float* ckh     = ws + 2113536;        // 8*256*256
    f16x8* wB      = (f16x8*)(ws + 2637824);      // ends 3162112 floats
    _Float16* xg   = (_Float16*)(ws + 3162112);   // 4*8192*512 f16 = 8388608 floats
    _Float16* xc   = (_Float16*)(ws + 11550720);  // 4*8192*256 f16 = 4194304 floats
    const size_t WS_NEEDED = (size_t)15745024 * 4; // 63.0 MB

    convert_weights<<<4096, 256, 0, stream>>>(gate_k, cand_k, gkh, ckh);
    conv_wprod<<<512, 256, 0, stream>>>(w1, wB);
    if (ws_size >= WS_NEEDED) {
        precompute_x<<<dim3(64, 6, 4), 512, 0, stream>>>(iq, ir, ql, rl, emb,
                                                         gate_k, cand_k, xg, xc);
        gru_encode_px<<<128, 1024, 0, stream>>>(ql, rl, gkh, gate_b, ckh, cand_b,
                                                xg, xc, Q, R);
    } else {
        gru_encode<<<128, 1024, 0, stream>>>(iq, ir, ql, rl, emb, gkh, gate_b,
                                             ckh, cand_b, Q, R);
    }
    dist_kernel<<<64, 256, 0, stream>>>(Q, R, dist);
    ab_kernel<<<dim3(4, 8, 2), 256, 0, stream>>>(Q, R, w1, A, Bv);
    pair_gemm<<<dim3(128, 8), 512, 0, stream>>>(Q, R, A, Bv, dist, nqi, nri,
                                                wB, w1, b1, w2, partial);
    final_reduce<<<128, 256, 0, stream>>>(partial, b2, out);
}